// Round 15
// baseline (622.685 us; speedup 1.0000x reference)
//
#include <hip/hip_runtime.h>

// ---------------- common helpers ----------------
typedef unsigned short ushortT;
typedef unsigned int uint32;
typedef __attribute__((ext_vector_type(8))) short short8;
typedef __attribute__((ext_vector_type(4))) float f32x4;

__device__ __forceinline__ ushortT f2bf(float f) {
    uint32 u = __float_as_uint(f);
    uint32 r = (u + 0x7fffu + ((u >> 16) & 1u)) >> 16;
    return (ushortT)r;
}
__device__ __forceinline__ float bf2f(uint32 v) {
    return __uint_as_float(v << 16);
}

__device__ __forceinline__ void unpack8(uint4 v, float* f) {
    f[0] = bf2f(v.x & 0xffffu); f[1] = bf2f(v.x >> 16);
    f[2] = bf2f(v.y & 0xffffu); f[3] = bf2f(v.y >> 16);
    f[4] = bf2f(v.z & 0xffffu); f[5] = bf2f(v.z >> 16);
    f[6] = bf2f(v.w & 0xffffu); f[7] = bf2f(v.w >> 16);
}

// async global->LDS, 16B per lane. LDS dest must be wave-uniform base;
// HW writes lane i at base + i*16.
typedef __attribute__((address_space(1))) const void gvoid;
typedef __attribute__((address_space(3))) void lvoid;
__device__ __forceinline__ void gld16(const ushortT* g, ushortT* l) {
    __builtin_amdgcn_global_load_lds((gvoid*)g, (lvoid*)l, 16, 0, 0);
}

// ---------------- fp32 -> bf16 convert: x (activation) ----------------
__global__ __launch_bounds__(256) void f32_to_bf16_kernel(
    const float* __restrict__ src, ushortT* __restrict__ dst, int n4)
{
    int i = blockIdx.x * 256 + threadIdx.x;
    if (i < n4) {
        float4 v = reinterpret_cast<const float4*>(src)[i];
        ushort4 o;
        o.x = f2bf(v.x); o.y = f2bf(v.y); o.z = f2bf(v.z); o.w = f2bf(v.w);
        reinterpret_cast<ushort4*>(dst)[i] = o;
    }
}

// ---------------- all 4 weight matrices -> one contiguous bf16 buffer ----
__global__ __launch_bounds__(256) void wconv_kernel(
    const float* __restrict__ s0, const float* __restrict__ s1,
    const float* __restrict__ s2, const float* __restrict__ s3,
    ushortT* __restrict__ dst)
{
    int i = blockIdx.x * 256 + threadIdx.x;      // 0 .. 4*262144-1
    const int wsel = i >> 18;
    const int off  = i & 262143;
    const float* s = (wsel == 0) ? s0 : (wsel == 1 ? s1 : (wsel == 2 ? s2 : s3));
    float4 v = reinterpret_cast<const float4*>(s)[off];
    ushort4 o;
    o.x = f2bf(v.x); o.y = f2bf(v.y); o.z = f2bf(v.z); o.w = f2bf(v.w);
    reinterpret_cast<ushort4*>(dst)[i] = o;
}

// ---------------- pack q/k/v biases into one 3072-float buffer ----------------
__global__ __launch_bounds__(256) void pack_bias_kernel(
    const float* __restrict__ bq, const float* __restrict__ bk,
    const float* __restrict__ bv, float* __restrict__ out)
{
    int i = blockIdx.x * 256 + threadIdx.x;   // 3072
    float v = (i < 1024) ? bq[i] : (i < 2048 ? bk[i - 1024] : bv[i - 2048]);
    out[i] = v;
}

// ---------------- RoPE cos/sin table: [T][16] float2 ----------------
__global__ __launch_bounds__(256) void rope_table_kernel(float2* __restrict__ tab)
{
    int idx = blockIdx.x * 256 + threadIdx.x;   // T*16 = 131072 entries
    int t = idx >> 4;
    int i = idx & 15;
    float inv = powf(10000.0f, -(float)i / 16.0f);
    float ang = (float)t * inv;
    tab[idx] = make_float2(cosf(ang), sinf(ang));
}

// swizzled LDS fragment read: region has 32-col rows; e ^= ((row>>1)&3)<<3
__device__ __forceinline__ short8 ldsfrag(const ushortT* region, int row, int g) {
    int e = (row << 5) + (g << 3);
    e ^= ((row >> 1) & 3) << 3;
    return *reinterpret_cast<const short8*>(region + e);
}

#define MC_ ((size_t)33554432)   // 32768 * 1024

// ---------------- 256x128-tile bf16 MFMA GEMM (r10 config + NT stores) ----
// GEMM campaign summary (r2-r13): five structures all land 500-650 TF with
// every pipe <=25%; sync-style (r7/r8), L2-BW (r9/r10), issue-port (r11),
// write-amp (r12), miss-tail (r8) theories all falsified by A/B. Inner loop
// FROZEN at the r10 config (proven 569us total).
// r14 change (sole, isolated): NONTEMPORAL stores on all outputs with no
// same-kernel same-XCD reuse (present, q/k/v bf16, y). Mechanism: per XCD a
// dispatch round = 8 tm x 8 tn blocks -> A 4MB + W 2MB = 6MB > 4MB L2, and
// 560MB of output writes evict A/W lines between the 8 tn-blocks' reads of
// a shared A panel (FETCH 175-199MB vs ~70 ideal). NT = evict-first hint;
// semantics-free (cannot alter values).
//
// Tile: 256x128, 512 thr = 8 waves (4m x 2n), wave 64x64 = 4x4 frags,
// BK=32, LDS 2 x 24KB = 48KB, rolled K-loop (r11 unroll regressed: icache),
// syncthreads-per-tile schedule. XCD co-location: per proj-phase 1024
// blocks = 8 xcd x (16 tm x 8 tn). W per phase = 2MB (L2 budget, r4/r9).
//
// MODE 3: merged qkv dispatch, grid 3072; proj = bid>>10 in {0,1,2}.
//   proj 0 (q): rope -> bf16; proj 1/2 (k/v): fp32 present (pre-rope,
//   (B,H,T,64)) + rope -> bf16.
// MODE 2: fp32 out, no rope (final projection), grid 1024, direct stores.
template<int MODE>
__global__ __launch_bounds__(512, 4) void gemm_wide_kernel(
    const ushortT* __restrict__ A,    // M x K bf16
    const ushortT* __restrict__ Wall, // MODE3: [wq;wk;wv] (3*1024 x K); MODE2: 1024 x K
    const float*   __restrict__ biasAll, // MODE3: 3072; MODE2: 1024
    const float2*  __restrict__ tab,  // rope table [T][16]
    ushortT*       __restrict__ CbAll,// MODE3: qlin (klin=+MC, vlin=+2MC)
    float*         __restrict__ CfAll,// MODE3: presK (presV=+MC); MODE2: MxN fp32
    int M, int N, int K)
{
    __shared__ ushortT lds[2 * 12288];  // 2 bufs x (A 8192 + B 4096) elems = 48 KB
    const int tid  = threadIdx.x;
    const int lane = tid & 63;
    const int wv   = tid >> 6;        // 0..7
    const int wm   = wv >> 1;         // 0..3  (64-row quarter of 256)
    const int wn   = wv & 1;          // 0..1  (64-col half of 128)
    const int g    = lane >> 4;       // k sub-block 0..3 (also C/D row group)
    const int rsel = lane & 15;

    // projection select (MODE 3) + per-projection block id
    const int bidAll = blockIdx.x;
    const int proj   = (MODE == 3) ? (bidAll >> 10) : 0;
    const int bid    = (MODE == 3) ? (bidAll & 1023) : bidAll;

    const ushortT* W    = Wall + (size_t)proj * 1024 * K;
    const float*   bias = biasAll + proj * 1024;

    // XCD co-location: 1024 blocks = 8 xcd x (16 tm x 8 tn)
    const int xi  = bid & 7;
    const int j   = bid >> 3;
    const int tn  = j & 7;
    const int tm  = xi * 16 + (j >> 3);
    const int m0  = tm * 256, n0 = tn * 128;

    // staging source: chunk c -> row c>>2, col8 = (c&3)^((c>>3)&3)
    // (pre-swizzled global source; LDS dest stays linear: chunk*16B)
    const int crow = tid >> 2;                       // 0..127
    const int ccol = ((tid & 3) ^ ((tid >> 3) & 3)) * 8;
    const ushortT* gA0 = A + (size_t)(m0 + crow) * K + ccol;   // A rows 0..127
    const ushortT* gA1 = gA0 + (size_t)128 * K;                // A rows 128..255
    const ushortT* gB0 = W + (size_t)(n0 + crow) * K + ccol;   // B rows 0..127

    // wave-uniform LDS dest bases (element offsets within a 12288-elem buffer)
    const int dA0 = wv * 512;           // A chunks tid       (rows 0..127)
    const int dA1 = 4096 + wv * 512;    // A chunks tid+512   (rows 128..255)
    const int dB  = 8192 + wv * 512;    // B chunks tid       (rows 0..127)

    #define STAGE(buf, t) { \
        ushortT* b_ = lds + (buf) * 12288; \
        gld16(gA0 + (t) * 32, b_ + dA0); \
        gld16(gA1 + (t) * 32, b_ + dA1); \
        gld16(gB0 + (t) * 32, b_ + dB); \
    }

    f32x4 acc[4][4] = {};
    const int NT = K >> 5;   // 32 K-tiles
    int cur = 0;

    STAGE(0, 0);

    #pragma unroll 1
    for (int t = 0; t < NT; ++t) {
        __syncthreads();   // drains vmcnt+lgkm: buf[cur] staged, prior reads done
        if (t + 1 < NT) STAGE(cur ^ 1, t + 1);

        const ushortT* ra = lds + cur * 12288;
        const ushortT* rb = ra + 8192;
        short8 Af[4], Bf[4];
        #pragma unroll
        for (int fm = 0; fm < 4; ++fm) Af[fm] = ldsfrag(ra, wm * 64 + fm * 16 + rsel, g);
        #pragma unroll
        for (int fn = 0; fn < 4; ++fn) Bf[fn] = ldsfrag(rb, wn * 64 + fn * 16 + rsel, g);
        #pragma unroll
        for (int fm = 0; fm < 4; ++fm)
            #pragma unroll
            for (int fn = 0; fn < 4; ++fn)
                acc[fm][fn] = __builtin_amdgcn_mfma_f32_16x16x32_bf16(Af[fm], Bf[fn], acc[fm][fn], 0, 0, 0);
        cur ^= 1;
    }
    #undef STAGE

    // epilogue: C/D layout col = rsel, row = g*4 + e (within 16x16 frag)
    #pragma unroll
    for (int fn = 0; fn < 4; ++fn) {
        const int colb = n0 + wn * 64 + fn * 16 + rsel;   // 0..1023
        const int d    = colb & 63;
        const float bv = bias[colb];
        #pragma unroll
        for (int fm = 0; fm < 4; ++fm) {
            const int rowbase = m0 + wm * 64 + fm * 16 + g * 4;
            #pragma unroll
            for (int e = 0; e < 4; ++e) {
                const int row = rowbase + e;
                const float val = acc[fm][fn][e] + bv;
                if (MODE == 2) {
                    // y: final output, never re-read -> NT (evict-first)
                    __builtin_nontemporal_store(val, &CfAll[(size_t)row * N + colb]);
                } else {
                    if (proj != 0) {
                        // present: (B, H, T, 64) fp32, pre-rope, never re-read -> NT
                        const int b = row >> 13, t = row & 8191;
                        const int h = colb >> 6;
                        __builtin_nontemporal_store(val,
                            &CfAll[(size_t)(proj - 1) * MC_ +
                                   (((size_t)b * 16 + h) * 8192 + t) * 64 + d]);
                    }
                    // rope: pair (d, d^1) sits at lane^1, same row
                    const float pv = __shfl_xor(val, 1, 64);
                    float ov = val;
                    if (d < 32) {
                        const int t = row & 8191;
                        const float2 cs = tab[t * 16 + (d >> 1)];
                        ov = (d & 1) ? fmaf(val, cs.x,  pv * cs.y)
                                     : fmaf(val, cs.x, -pv * cs.y);
                    }
                    // q/k/v bf16: re-read only by natt (mostly other XCDs) -> NT
                    __builtin_nontemporal_store(f2bf(ov),
                        &CbAll[(size_t)proj * MC_ + (size_t)row * 1024 + colb]);
                }
            }
        }
    }
}

// ---------------- neighborhood attention ----------------
// wave = 8 queries x 8 dim-chunks; lane = tloc*8 + c  (8 consecutive lanes
// cover one contiguous 128B row segment). q/k/v already roped.
// XCD-chunk swizzle (r13, bijective 16384 = 8 x 2048): contiguous t-range
// per XCD keeps the 7-wide K/V streaming window in one L2.
__global__ __launch_bounds__(256) void natt_kernel(
    const ushortT* __restrict__ Q,
    const ushortT* __restrict__ Kl,
    const ushortT* __restrict__ Vl,
    ushortT*       __restrict__ O)
{
    const int T = 8192;
    const int tid  = threadIdx.x;
    const int lane = tid & 63;
    const int tloc = lane >> 3;
    const int c    = lane & 7;

    // XCD-chunk swizzle: grid 16384 = 8 xcd x 2048 logical blocks
    const int sbid = (blockIdx.x & 7) * 2048 + (blockIdx.x >> 3);
    const int wq   = sbid * 4 + (tid >> 6);          // wave-group id
    const int qidx = wq * 8 + tloc;
    const int t = qidx & (T - 1);
    const int h = (qidx >> 13) & 15;
    const int b = qidx >> 17;

    const int shifts[4] = {0, 2, 3, 4};
    const int sh = shifts[h >> 2];
    const int dd = 1 << sh;

    const int r  = t & (dd - 1);
    const int p  = t >> sh;
    const int Lr = ((T - 1 - r) >> sh) + 1;
    int s = p - 3;
    const int smax = Lr - 7;
    s = s < 0 ? 0 : (s > smax ? smax : s);
    const int tbase = r + (s << sh);

    const size_t qoff = ((size_t)(b * T + t)) * 1024 + h * 64 + c * 8;
    float qf[8];
    unpack8(*reinterpret_cast<const uint4*>(Q + qoff), qf);

    const size_t cbase = ((size_t)b * T) * 1024 + h * 64 + c * 8;

    float sc[7];
    #pragma unroll
    for (int j = 0; j < 7; ++j) {
        const int tj = tbase + (j << sh);
        float kf[8];
        unpack8(*reinterpret_cast<const uint4*>(Kl + cbase + (size_t)tj * 1024), kf);
        float pp = 0.f;
        #pragma unroll
        for (int i = 0; i < 8; ++i) pp = fmaf(qf[i], kf[i], pp);
        pp += __shfl_xor(pp, 1, 64);
        pp += __shfl_xor(pp, 2, 64);
        pp += __shfl_xor(pp, 4, 64);
        sc[j] = pp;
    }

    float mx = sc[0];
    #pragma unroll
    for (int j = 1; j < 7; ++j) mx = fmaxf(mx, sc[j]);
    float den = 0.f;
    #pragma unroll
    for (int j = 0; j < 7; ++j) { sc[j] = __expf(sc[j] - mx); den += sc[j]; }
    const float inv = 1.0f / den;

    float out[8] = {};
    #pragma unroll
    for (int j = 0; j < 7; ++j) {
        const int tj = tbase + (j << sh);
        float vf[8];
        unpack8(*reinterpret_cast<const uint4*>(Vl + cbase + (size_t)tj * 1024), vf);
        #pragma unroll
        for (int i = 0; i < 8; ++i) out[i] = fmaf(sc[j], vf[i], out[i]);
    }

    short8 ov;
    #pragma unroll
    for (int i = 0; i < 8; ++i) ov[i] = (short)f2bf(out[i] * inv);
    // attn out: re-read by out-proj (cross-XCD) -> NT protects natt's own
    // K/V window reuse in L2 from output pollution
    __builtin_nontemporal_store(ov, reinterpret_cast<short8*>(const_cast<ushortT*>(O + qoff)));
}

// ---------------- launcher ----------------
extern "C" void kernel_launch(void* const* d_in, const int* in_sizes, int n_in,
                              void* d_out, int out_size, void* d_ws, size_t ws_size,
                              hipStream_t stream)
{
    const float* x  = (const float*)d_in[0];
    const float* wq = (const float*)d_in[1];
    const float* bq = (const float*)d_in[2];
    const float* wk = (const float*)d_in[3];
    const float* bk = (const float*)d_in[4];
    const float* wv = (const float*)d_in[5];
    const float* bv = (const float*)d_in[6];
    const float* wp = (const float*)d_in[7];
    const float* bp = (const float*)d_in[8];

    const int B = 4, T = 8192, C = 1024;
    const int M = B * T;                    // 32768
    const size_t MC = (size_t)M * C;        // 33,554,432

    char* ws = (char*)d_ws;
    ushortT* xb    = (ushortT*)ws;                                  // 64MB (reused as attn out)
    ushortT* wallb = (ushortT*)(ws + (size_t)64 * 1024 * 1024);     // 8MB: [wq][wk][wv][wp]
    ushortT* wpb   = wallb + (size_t)3 * C * C;
    ushortT* qlin  = (ushortT*)(ws + (size_t)72 * 1024 * 1024);     // 64MB (klin,vlin follow)
    ushortT* klin  = qlin + MC;
    ushortT* vlin  = klin + MC;
    float2*  tab   = (float2*)(ws + (size_t)264 * 1024 * 1024);     // 1MB
    float*   bqkv  = (float*)(ws + (size_t)266 * 1024 * 1024);      // 12KB

    float* y     = (float*)d_out;
    float* presK = y + MC;                  // presV = presK + MC (contiguous)

    rope_table_kernel<<<512, 256, 0, stream>>>(tab);
    pack_bias_kernel<<<12, 256, 0, stream>>>(bq, bk, bv, bqkv);

    f32_to_bf16_kernel<<<(int)(MC / 4 / 256), 256, 0, stream>>>(x, xb, (int)(MC / 4));
    wconv_kernel<<<4 * (C * C / 4) / 256, 256, 0, stream>>>(wq, wk, wv, wp, wallb);

    // merged qkv dispatch: grid 3072 = 3 proj x 1024 blocks (256x128 tiles)
    gemm_wide_kernel<3><<<3072, 512, 0, stream>>>(
        xb, wallb, bqkv, tab, qlin, presK, M, C, C);

    natt_kernel<<<(B * 16 * T) / 32, 256, 0, stream>>>(qlin, klin, vlin, xb);

    // output projection: grid 1024
    gemm_wide_kernel<2><<<1024, 512, 0, stream>>>(
        xb, wpb, bp, tab, nullptr, y, M, C, C);
}

// Round 16
// 596.968 us; speedup vs baseline: 1.0431x; 1.0431x over previous
//
#include <hip/hip_runtime.h>

// ---------------- common helpers ----------------
typedef unsigned short ushortT;
typedef unsigned int uint32;
typedef __attribute__((ext_vector_type(8))) short short8;
typedef __attribute__((ext_vector_type(4))) float f32x4;

__device__ __forceinline__ ushortT f2bf(float f) {
    uint32 u = __float_as_uint(f);
    uint32 r = (u + 0x7fffu + ((u >> 16) & 1u)) >> 16;
    return (ushortT)r;
}
__device__ __forceinline__ float bf2f(uint32 v) {
    return __uint_as_float(v << 16);
}

__device__ __forceinline__ void unpack8(uint4 v, float* f) {
    f[0] = bf2f(v.x & 0xffffu); f[1] = bf2f(v.x >> 16);
    f[2] = bf2f(v.y & 0xffffu); f[3] = bf2f(v.y >> 16);
    f[4] = bf2f(v.z & 0xffffu); f[5] = bf2f(v.z >> 16);
    f[6] = bf2f(v.w & 0xffffu); f[7] = bf2f(v.w >> 16);
}

// async global->LDS, 16B per lane. LDS dest must be wave-uniform base;
// HW writes lane i at base + i*16.
typedef __attribute__((address_space(1))) const void gvoid;
typedef __attribute__((address_space(3))) void lvoid;
__device__ __forceinline__ void gld16(const ushortT* g, ushortT* l) {
    __builtin_amdgcn_global_load_lds((gvoid*)g, (lvoid*)l, 16, 0, 0);
}

// ---------------- fp32 -> bf16 convert: x (activation) ----------------
__global__ __launch_bounds__(256) void f32_to_bf16_kernel(
    const float* __restrict__ src, ushortT* __restrict__ dst, int n4)
{
    int i = blockIdx.x * 256 + threadIdx.x;
    if (i < n4) {
        float4 v = reinterpret_cast<const float4*>(src)[i];
        ushort4 o;
        o.x = f2bf(v.x); o.y = f2bf(v.y); o.z = f2bf(v.z); o.w = f2bf(v.w);
        reinterpret_cast<ushort4*>(dst)[i] = o;
    }
}

// ---------------- all 4 weight matrices -> one contiguous bf16 buffer ----
__global__ __launch_bounds__(256) void wconv_kernel(
    const float* __restrict__ s0, const float* __restrict__ s1,
    const float* __restrict__ s2, const float* __restrict__ s3,
    ushortT* __restrict__ dst)
{
    int i = blockIdx.x * 256 + threadIdx.x;      // 0 .. 4*262144-1
    const int wsel = i >> 18;
    const int off  = i & 262143;
    const float* s = (wsel == 0) ? s0 : (wsel == 1 ? s1 : (wsel == 2 ? s2 : s3));
    float4 v = reinterpret_cast<const float4*>(s)[off];
    ushort4 o;
    o.x = f2bf(v.x); o.y = f2bf(v.y); o.z = f2bf(v.z); o.w = f2bf(v.w);
    reinterpret_cast<ushort4*>(dst)[i] = o;
}

// ---------------- pack q/k/v biases into one 3072-float buffer ----------------
__global__ __launch_bounds__(256) void pack_bias_kernel(
    const float* __restrict__ bq, const float* __restrict__ bk,
    const float* __restrict__ bv, float* __restrict__ out)
{
    int i = blockIdx.x * 256 + threadIdx.x;   // 3072
    float v = (i < 1024) ? bq[i] : (i < 2048 ? bk[i - 1024] : bv[i - 2048]);
    out[i] = v;
}

// ---------------- RoPE cos/sin table: [T][16] float2 ----------------
__global__ __launch_bounds__(256) void rope_table_kernel(float2* __restrict__ tab)
{
    int idx = blockIdx.x * 256 + threadIdx.x;   // T*16 = 131072 entries
    int t = idx >> 4;
    int i = idx & 15;
    float inv = powf(10000.0f, -(float)i / 16.0f);
    float ang = (float)t * inv;
    tab[idx] = make_float2(cosf(ang), sinf(ang));
}

#define MC_ ((size_t)33554432)   // 32768 * 1024

// ---------------- 256x256-tile 8-phase bf16 MFMA GEMM ----------------
// r15 post-mortem: NT stores cut FETCH/WRITE but regressed dur (NT path
// cost > eviction cost) -> reverted. Our 2-phase loop sits AT the known
// ~600 TF structural ceiling (stage+vmcnt+barrier overhead). This kernel
// is the 8-phase counted-vmcnt template (T2+T3+T4+T5), re-derived:
//
// Geometry: BM=BN=256, BK=64, 512 thr = 8 waves (wm=wv>>2 in {0,1} row
// half, wn=wv&3 col quarter). Per-wave out 128x64 = acc[8][4]. LDS 128KB:
// A[slot][kk]: 256x32 bf16 (8KB... 8192 elems) at slot*16384+kk*8192;
// B likewise at +32768. slot = tile&1.
// Phases (per iter j, tiles t0=2j slot0, t0+1 slot1):
//   P1(s0,k0,rfh0: 4A+4B ds_read) P2(s0,k0,rfh1: 4A) P3(s0,k1,rfh0)
//   P4(s0,k1,rfh1) P5..P8 same on slot1. 16 MFMA per phase.
// Stage unit = A+B of one (tile,kk) = 4 gld_lds/thread, issued at the
// phase where that LDS region is freed:
//   P1: (t0+1,k1)  [slot1-k1 last read prev-iter P7/P8]
//   P3: (t0+2,k0)  [slot0-k0 last read P1/P2]
//   P5: (t0+2,k1)  [slot0-k1 last read P3/P4]
//   P7: (t0+3,k0)  [slot1-k0 last read P5/P6]
// Freed-ness is safe: last readers' ds_reads completed before their MFMA
// (lgkmcnt(0)) before that phase's trailing barrier; stages issue after.
// vmcnt(4) at P4 and P8 ONLY (in-order retirement: lands all but newest
// unit). Proof of read-gating:
//   P1 reads (2j,k0) staged j-1@P3: landed by j-1@P8 vmcnt(4) [leaves P7]
//   P3 reads (2j,k1) staged j-1@P5: landed by j-1@P8 vmcnt(4)
//   P5 reads (2j+1,k0) staged j-1@P7: landed by j@P4 vmcnt(4) [leaves P3]
//   P7 reads (2j+1,k1) staged j@P1:   landed by j@P4 vmcnt(4)
// Prologue: stage (0,k0),(0,k1),(1,k0); vmcnt(4); barrier. Tail j=7:
// skip P3/P5/P7 stages, vmcnt(0) at P4.
// Swizzle (64B rows, both-sides involution): elem e ^= ((row>>1)&3)<<3.
// ds_read bank check: lanes rsel 0..15 -> 2 lanes/bank-group = free (m136).
// Rule #18: lgkmcnt(0) is followed by sched_barrier(0) before each MFMA
// cluster; setprio(1) wraps the 16-MFMA cluster (T5, gated on by T3).
//
// MODE 3: merged qkv, grid 1536; proj=bid>>9. q: rope->bf16; k/v: fp32
// present (pre-rope,(B,H,T,64)) + rope->bf16. MODE 2: fp32 out, grid 512.

#define STAGEU(tile, kk) { \
    ushortT* la_ = lds + ((tile) & 1) * 16384 + (kk) * 8192 + wv * 512; \
    ushortT* lb_ = la_ + 32768; \
    const ushortT* ga_ = pA + (tile) * 64 + (kk) * 32; \
    const ushortT* gb_ = pB + (tile) * 64 + (kk) * 32; \
    gld16(ga_, la_); gld16(ga_ + (size_t)128 * K, la_ + 4096); \
    gld16(gb_, lb_); gld16(gb_ + (size_t)128 * K, lb_ + 4096); }

#define RDA(s, kk, rfh) { \
    const ushortT* ra_ = lds + (s) * 16384 + (kk) * 8192 + aoff + (rfh) * 2048; \
    Af0 = *reinterpret_cast<const short8*>(ra_); \
    Af1 = *reinterpret_cast<const short8*>(ra_ + 512); \
    Af2 = *reinterpret_cast<const short8*>(ra_ + 1024); \
    Af3 = *reinterpret_cast<const short8*>(ra_ + 1536); }

#define RDB(s, kk) { \
    const ushortT* rb_ = lds + (s) * 16384 + (kk) * 8192 + boff; \
    Bf0 = *reinterpret_cast<const short8*>(rb_); \
    Bf1 = *reinterpret_cast<const short8*>(rb_ + 512); \
    Bf2 = *reinterpret_cast<const short8*>(rb_ + 1024); \
    Bf3 = *reinterpret_cast<const short8*>(rb_ + 1536); }

#define SYNCA \
    __builtin_amdgcn_s_barrier(); \
    asm volatile("s_waitcnt lgkmcnt(0)" ::: "memory"); \
    __builtin_amdgcn_sched_barrier(0);

#define MM1(RF, CF, AF, BF) \
    acc[RF][CF] = __builtin_amdgcn_mfma_f32_16x16x32_bf16(AF, BF, acc[RF][CF], 0, 0, 0);

#define MMQ(RFH) \
    __builtin_amdgcn_s_setprio(1); \
    MM1((RFH)*4+0, 0, Af0, Bf0) MM1((RFH)*4+0, 1, Af0, Bf1) \
    MM1((RFH)*4+0, 2, Af0, Bf2) MM1((RFH)*4+0, 3, Af0, Bf3) \
    MM1((RFH)*4+1, 0, Af1, Bf0) MM1((RFH)*4+1, 1, Af1, Bf1) \
    MM1((RFH)*4+1, 2, Af1, Bf2) MM1((RFH)*4+1, 3, Af1, Bf3) \
    MM1((RFH)*4+2, 0, Af2, Bf0) MM1((RFH)*4+2, 1, Af2, Bf1) \
    MM1((RFH)*4+2, 2, Af2, Bf2) MM1((RFH)*4+2, 3, Af2, Bf3) \
    MM1((RFH)*4+3, 0, Af3, Bf0) MM1((RFH)*4+3, 1, Af3, Bf1) \
    MM1((RFH)*4+3, 2, Af3, Bf2) MM1((RFH)*4+3, 3, Af3, Bf3) \
    __builtin_amdgcn_s_setprio(0); \
    __builtin_amdgcn_s_barrier();

#define VM4 asm volatile("s_waitcnt vmcnt(4)" ::: "memory");
#define VM0 asm volatile("s_waitcnt vmcnt(0)" ::: "memory");

template<int MODE>
__global__ __launch_bounds__(512, 2) void gemm8_kernel(
    const ushortT* __restrict__ A,    // M x K bf16  (K == 1024)
    const ushortT* __restrict__ Wall, // MODE3: [wq;wk;wv]; MODE2: wp
    const float*   __restrict__ biasAll, // MODE3: 3072; MODE2: 1024
    const float2*  __restrict__ tab,  // rope table [T][16]
    ushortT*       __restrict__ CbAll,// MODE3: qlin (klin=+MC, vlin=+2MC)
    float*         __restrict__ CfAll,// MODE3: presK (presV=+MC); MODE2: MxN fp32
    int M, int N, int K)
{
    extern __shared__ ushortT lds[];   // 131072 B
    const int tid  = threadIdx.x;
    const int lane = tid & 63;
    const int wv   = tid >> 6;        // 0..7
    const int wm   = wv >> 2;         // 0..1  (128-row half)
    const int wn   = wv & 3;          // 0..3  (64-col quarter)
    const int g    = lane >> 4;       // k sub-block 0..3 (also C/D row group)
    const int rsel = lane & 15;

    const int bidAll = blockIdx.x;
    const int proj   = (MODE == 3) ? (bidAll >> 9) : 0;
    const int bid    = (MODE == 3) ? (bidAll & 511) : bidAll;

    const ushortT* W    = Wall + (size_t)proj * 1024 * K;
    const float*   bias = biasAll + proj * 1024;

    // XCD co-location: 512 blocks = 8 xcd x (16 tm x 4 tn)
    const int xi = bid & 7;
    const int jb = bid >> 3;
    const int tn = jb & 3;
    const int tm = xi * 16 + (jb >> 2);
    const int m0 = tm * 256, n0 = tn * 256;

    // staging source (pre-swizzled): chunk c -> row c>>2 (of 256),
    // granule glog = (c&3) ^ ((c>>3)&3); chunks c = tid and tid+512
    // share glog (512 ≡ 0 mod 8) and differ by 128 rows.
    const int g0 = (tid & 3) ^ ((tid >> 3) & 3);
    const ushortT* pA = A + (size_t)(m0 + (tid >> 2)) * K + g0 * 8;
    const ushortT* pB = W + (size_t)(n0 + (tid >> 2)) * K + g0 * 8;

    // swizzled ds_read bases: row-part*32 + (g ^ ((rsel>>1)&3))*8
    const int gsw  = g ^ ((rsel >> 1) & 3);
    const int aoff = (wm * 128 + rsel) * 32 + gsw * 8;           // + rf*512
    const int boff = 32768 + (wn * 64 + rsel) * 32 + gsw * 8;    // + cf*512

    f32x4 acc[8][4] = {};
    short8 Af0, Af1, Af2, Af3, Bf0, Bf1, Bf2, Bf3;

    // prologue: (0,k0),(0,k1),(1,k0) staged; land first two.
    STAGEU(0, 0);
    STAGEU(0, 1);
    STAGEU(1, 0);
    VM4;
    __builtin_amdgcn_s_barrier();

    #pragma unroll 1
    for (int j = 0; j < 8; ++j) {
        const int t0 = 2 * j;
        // P1: slot0, k0, rfh0
        RDA(0, 0, 0); RDB(0, 0);
        STAGEU(t0 + 1, 1);
        SYNCA; MMQ(0);
        // P2: slot0, k0, rfh1
        RDA(0, 0, 1);
        SYNCA; MMQ(1);
        // P3: slot0, k1, rfh0
        RDA(0, 1, 0); RDB(0, 1);
        if (j < 7) { STAGEU(t0 + 2, 0); }
        SYNCA; MMQ(0);
        // P4: slot0, k1, rfh1
        RDA(0, 1, 1);
        if (j < 7) { VM4 } else { VM0 }
        SYNCA; MMQ(1);
        // P5: slot1, k0, rfh0
        RDA(1, 0, 0); RDB(1, 0);
        if (j < 7) { STAGEU(t0 + 2, 1); }
        SYNCA; MMQ(0);
        // P6: slot1, k0, rfh1
        RDA(1, 0, 1);
        SYNCA; MMQ(1);
        // P7: slot1, k1, rfh0
        RDA(1, 1, 0); RDB(1, 1);
        if (j < 7) { STAGEU(t0 + 3, 0); }
        SYNCA; MMQ(0);
        // P8: slot1, k1, rfh1
        RDA(1, 1, 1);
        if (j < 7) { VM4 }
        SYNCA; MMQ(1);
    }

    // epilogue: C/D layout col = rsel, row = g*4 + e (within 16x16 frag)
    #pragma unroll
    for (int cf = 0; cf < 4; ++cf) {
        const int colb = n0 + wn * 64 + cf * 16 + rsel;   // 0..1023
        const int d    = colb & 63;
        const float bv = bias[colb];
        #pragma unroll
        for (int rf = 0; rf < 8; ++rf) {
            const int rowbase = m0 + wm * 128 + rf * 16 + g * 4;
            #pragma unroll
            for (int e = 0; e < 4; ++e) {
                const int row = rowbase + e;
                const float val = acc[rf][cf][e] + bv;
                if (MODE == 2) {
                    CfAll[(size_t)row * N + colb] = val;
                } else {
                    if (proj != 0) {
                        // present: (B, H, T, 64) fp32, pre-rope
                        const int b = row >> 13, t = row & 8191;
                        const int h = colb >> 6;
                        CfAll[(size_t)(proj - 1) * MC_ +
                              (((size_t)b * 16 + h) * 8192 + t) * 64 + d] = val;
                    }
                    // rope: pair (d, d^1) sits at lane^1, same row
                    const float pv = __shfl_xor(val, 1, 64);
                    float ov = val;
                    if (d < 32) {
                        const int t = row & 8191;
                        const float2 cs = tab[t * 16 + (d >> 1)];
                        ov = (d & 1) ? fmaf(val, cs.x,  pv * cs.y)
                                     : fmaf(val, cs.x, -pv * cs.y);
                    }
                    CbAll[(size_t)proj * MC_ + (size_t)row * 1024 + colb] = f2bf(ov);
                }
            }
        }
    }
}

// ---------------- neighborhood attention ----------------
// wave = 8 queries x 8 dim-chunks; lane = tloc*8 + c. q/k/v already roped.
// XCD-chunk swizzle (bijective 16384 = 8 x 2048): contiguous t-range per
// XCD keeps the 7-wide K/V streaming window in one L2.
__global__ __launch_bounds__(256) void natt_kernel(
    const ushortT* __restrict__ Q,
    const ushortT* __restrict__ Kl,
    const ushortT* __restrict__ Vl,
    ushortT*       __restrict__ O)
{
    const int T = 8192;
    const int tid  = threadIdx.x;
    const int lane = tid & 63;
    const int tloc = lane >> 3;
    const int c    = lane & 7;

    const int sbid = (blockIdx.x & 7) * 2048 + (blockIdx.x >> 3);
    const int wq   = sbid * 4 + (tid >> 6);          // wave-group id
    const int qidx = wq * 8 + tloc;
    const int t = qidx & (T - 1);
    const int h = (qidx >> 13) & 15;
    const int b = qidx >> 17;

    const int shifts[4] = {0, 2, 3, 4};
    const int sh = shifts[h >> 2];
    const int dd = 1 << sh;

    const int r  = t & (dd - 1);
    const int p  = t >> sh;
    const int Lr = ((T - 1 - r) >> sh) + 1;
    int s = p - 3;
    const int smax = Lr - 7;
    s = s < 0 ? 0 : (s > smax ? smax : s);
    const int tbase = r + (s << sh);

    const size_t qoff = ((size_t)(b * T + t)) * 1024 + h * 64 + c * 8;
    float qf[8];
    unpack8(*reinterpret_cast<const uint4*>(Q + qoff), qf);

    const size_t cbase = ((size_t)b * T) * 1024 + h * 64 + c * 8;

    float sc[7];
    #pragma unroll
    for (int j = 0; j < 7; ++j) {
        const int tj = tbase + (j << sh);
        float kf[8];
        unpack8(*reinterpret_cast<const uint4*>(Kl + cbase + (size_t)tj * 1024), kf);
        float pp = 0.f;
        #pragma unroll
        for (int i = 0; i < 8; ++i) pp = fmaf(qf[i], kf[i], pp);
        pp += __shfl_xor(pp, 1, 64);
        pp += __shfl_xor(pp, 2, 64);
        pp += __shfl_xor(pp, 4, 64);
        sc[j] = pp;
    }

    float mx = sc[0];
    #pragma unroll
    for (int j = 1; j < 7; ++j) mx = fmaxf(mx, sc[j]);
    float den = 0.f;
    #pragma unroll
    for (int j = 0; j < 7; ++j) { sc[j] = __expf(sc[j] - mx); den += sc[j]; }
    const float inv = 1.0f / den;

    float out[8] = {};
    #pragma unroll
    for (int j = 0; j < 7; ++j) {
        const int tj = tbase + (j << sh);
        float vf[8];
        unpack8(*reinterpret_cast<const uint4*>(Vl + cbase + (size_t)tj * 1024), vf);
        #pragma unroll
        for (int i = 0; i < 8; ++i) out[i] = fmaf(sc[j], vf[i], out[i]);
    }

    short8 ov;
    #pragma unroll
    for (int i = 0; i < 8; ++i) ov[i] = (short)f2bf(out[i] * inv);
    *reinterpret_cast<short8*>(const_cast<ushortT*>(O + qoff)) = ov;
}

// ---------------- launcher ----------------
extern "C" void kernel_launch(void* const* d_in, const int* in_sizes, int n_in,
                              void* d_out, int out_size, void* d_ws, size_t ws_size,
                              hipStream_t stream)
{
    const float* x  = (const float*)d_in[0];
    const float* wq = (const float*)d_in[1];
    const float* bq = (const float*)d_in[2];
    const float* wk = (const float*)d_in[3];
    const float* bk = (const float*)d_in[4];
    const float* wv = (const float*)d_in[5];
    const float* bv = (const float*)d_in[6];
    const float* wp = (const float*)d_in[7];
    const float* bp = (const float*)d_in[8];

    const int B = 4, T = 8192, C = 1024;
    const int M = B * T;                    // 32768
    const size_t MC = (size_t)M * C;        // 33,554,432

    char* ws = (char*)d_ws;
    ushortT* xb    = (ushortT*)ws;                                  // 64MB (reused as attn out)
    ushortT* wallb = (ushortT*)(ws + (size_t)64 * 1024 * 1024);     // 8MB: [wq][wk][wv][wp]
    ushortT* wpb   = wallb + (size_t)3 * C * C;
    ushortT* qlin  = (ushortT*)(ws + (size_t)72 * 1024 * 1024);     // 64MB (klin,vlin follow)
    ushortT* klin  = qlin + MC;
    ushortT* vlin  = klin + MC;
    float2*  tab   = (float2*)(ws + (size_t)264 * 1024 * 1024);     // 1MB
    float*   bqkv  = (float*)(ws + (size_t)266 * 1024 * 1024);      // 12KB

    float* y     = (float*)d_out;
    float* presK = y + MC;                  // presV = presK + MC (contiguous)

    // allow 128 KB dynamic LDS on the GEMM instantiations (idempotent)
    hipFuncSetAttribute((const void*)gemm8_kernel<3>,
                        hipFuncAttributeMaxDynamicSharedMemorySize, 131072);
    hipFuncSetAttribute((const void*)gemm8_kernel<2>,
                        hipFuncAttributeMaxDynamicSharedMemorySize, 131072);

    rope_table_kernel<<<512, 256, 0, stream>>>(tab);
    pack_bias_kernel<<<12, 256, 0, stream>>>(bq, bk, bv, bqkv);

    f32_to_bf16_kernel<<<(int)(MC / 4 / 256), 256, 0, stream>>>(x, xb, (int)(MC / 4));
    wconv_kernel<<<4 * (C * C / 4) / 256, 256, 0, stream>>>(wq, wk, wv, wp, wallb);

    // merged qkv: grid 1536 = 3 proj x 512 blocks (256x256 tiles)
    gemm8_kernel<3><<<1536, 512, 131072, stream>>>(
        xb, wallb, bqkv, tab, qlin, presK, M, C, C);

    natt_kernel<<<(B * 16 * T) / 32, 256, 0, stream>>>(qlin, klin, vlin, xb);

    // output projection: grid 512
    gemm8_kernel<2><<<512, 512, 131072, stream>>>(
        xb, wpb, bp, tab, nullptr, y, M, C, C);
}